// Round 19
// baseline (382.406 us; speedup 1.0000x reference)
//
#include <hip/hip_runtime.h>

#define NND 50000
#define NED 800000
#define NF  128
#define NH  64
#define BN_EPS 1e-5
#define NCOPY 8    // stats slot-copies (f32)
#define SCB  256   // scan chunk
#define NSB  ((NND + SCB - 1) / SCB)   // 196 scan blocks
#define XNODES (NND / 8)               // 6250 nodes per XCD slice
#define FCH  196                       // edge chunks (1024 int4 each) per XCD pass
#define NT   782                       // transform/mlp tiles
#define PGRID (FCH * 8)                // 1568 edge-partition blocks
#define NE4  (NED / 4)                 // 200000 int4 edge quads

// ---- workspace byte offsets (16B aligned) ----
// hB/aggB are COLUMN-SPLIT: unsigned[2][NND][16 bf16x2 words]; half h = cols [h*32,h*32+32)
// Each half = 3.2 MB -> fits one XCD's 4MB L2 during its agg half-kernel.
#define WS_HB     0                          // 6,400,000 B
#define WS_AGG    6400000                    // 6,400,000 B
#define WS_STATS  12800000                   // float[4][NCOPY*128] = 16 KB
#define WS_DEG    (WS_STATS + 4*NCOPY*128*4) // int[NND]  (memset'd with stats)
#define WS_OFFS   (WS_DEG + NND*4)           // int[NND+4]
#define WS_CUR    (WS_OFFS + (NND+4)*4)      // int[NND]
#define WS_PARTS  (WS_CUR + NND*4)           // int[256]
#define WS_ESRC   (WS_PARTS + 256*4)         // int[NED]

// ---- bf16 helpers (storage-only; all math in f32) ----
__device__ __forceinline__ unsigned bfrn(float x) {
    unsigned u = __float_as_uint(x);
    return (u + 0x7fffu + ((u >> 16) & 1u)) >> 16;
}
__device__ __forceinline__ unsigned pk(float lo, float hi) {
    return bfrn(lo) | (bfrn(hi) << 16);
}
__device__ __forceinline__ float ulo(unsigned u) { return __uint_as_float(u << 16); }
__device__ __forceinline__ float uhi(unsigned u) { return __uint_as_float(u & 0xffff0000u); }
__device__ __forceinline__ void upadd(unsigned u, float& lo, float& hi) {
    lo += ulo(u); hi += uhi(u);
}

// derive BN scale/shift for column c from f32 slot-copy stats
__device__ __forceinline__ void bn_derive(const float* __restrict__ st, int c,
                                          const float* __restrict__ g,
                                          const float* __restrict__ b,
                                          float& sc, float& sh) {
    float sum = 0.f, ssq = 0.f;
#pragma unroll
    for (int cp = 0; cp < NCOPY; ++cp) {
        sum += st[cp * 128 + c];
        ssq += st[cp * 128 + 64 + c];
    }
    double mu  = (double)sum / (double)NND;
    double var = (double)ssq / (double)NND - mu * mu;
    if (var < 0.0) var = 0.0;
    double rs = 1.0 / sqrt(var + BN_EPS);
    double scd = (double)g[c] * rs;
    sc = (float)scd;
    sh = (float)((double)b[c] - mu * scd);
}

// ---------------- FUSED: transform (blocks [0,NT)) || degree count (blocks [NT,NT+PGRID)) ----
__global__ __launch_bounds__(256) void k_dtf(const int* __restrict__ dst,
                                             int* __restrict__ deg,
                                             const float* __restrict__ x,
                                             const float* __restrict__ Wt,
                                             const float* __restrict__ bt,
                                             unsigned* __restrict__ hB,
                                             float* __restrict__ stats) {
    __shared__ __align__(16) unsigned Wlu[NF * NH / 2]; // 16 KB, bf16-packed
    __shared__ __align__(16) float sT[64 * 68];         // 17.4 KB
    int tid = threadIdx.x;

    if (blockIdx.x >= NT) {
        // ---- degree-count body (R15): batch all 4 stream loads up-front ----
        int dbid = blockIdx.x - NT;
        int xcd = dbid & 7;
        int chunk = dbid >> 3;
        int lo = xcd * XNODES;
        const int4* d4 = (const int4*)dst;
        int4 d[4];
#pragma unroll
        for (int r = 0; r < 4; ++r) {
            int i = chunk * 1024 + r * 256 + tid;
            int ii = i < NE4 ? i : NE4 - 1;
            d[r] = d4[ii];
            if (i >= NE4) d[r] = make_int4(-1, -1, -1, -1);
        }
#pragma unroll
        for (int r = 0; r < 4; ++r) {
            if ((unsigned)(d[r].x - lo) < XNODES) atomicAdd(&deg[d[r].x], 1);
            if ((unsigned)(d[r].y - lo) < XNODES) atomicAdd(&deg[d[r].y], 1);
            if ((unsigned)(d[r].z - lo) < XNODES) atomicAdd(&deg[d[r].z], 1);
            if ((unsigned)(d[r].w - lo) < XNODES) atomicAdd(&deg[d[r].w], 1);
        }
        return;
    }

    // ---- transform body: hB write goes to the column-split layout ----
    int tile = blockIdx.x;
    int base = tile * 64;
    const float4* x4 = (const float4*)x;

#pragma unroll
    for (int r = 0; r < 8; ++r) {
        int i4 = r * 256 + tid;
        float4 w = ((const float4*)Wt)[i4];
        uint2 wp; wp.x = pk(w.x, w.y); wp.y = pk(w.z, w.w);
        ((uint2*)Wlu)[i4] = wp;
    }

    int wave = tid >> 6, lane = tid & 63;
    int ti = lane & 7, tj = lane >> 3;
    int cw = wave * 32 + tj * 4;          // compute waves 0-1: output cols

    float acc[8][4];
#pragma unroll
    for (int i = 0; i < 8; ++i)
#pragma unroll
        for (int j = 0; j < 4; ++j) acc[i][j] = 0.f;

    for (int ch = 0; ch < 2; ++ch) {
        __syncthreads();
        float4 pf[4];
#pragma unroll
        for (int s = 0; s < 4; ++s) {
            int flat = s * 256 + tid;
            int nl = flat >> 4, q = flat & 15;
            pf[s] = make_float4(0.f, 0.f, 0.f, 0.f);
            if (base + nl < NND) pf[s] = x4[(size_t)(base + nl) * 32 + ch * 16 + q];
        }
#pragma unroll
        for (int s = 0; s < 4; ++s) {
            int flat = s * 256 + tid;
            int nl = flat >> 4, q = flat & 15;
            sT[(q * 4 + 0) * 68 + nl] = pf[s].x;
            sT[(q * 4 + 1) * 68 + nl] = pf[s].y;
            sT[(q * 4 + 2) * 68 + nl] = pf[s].z;
            sT[(q * 4 + 3) * 68 + nl] = pf[s].w;
        }
        __syncthreads();
        if (tid < 128) {
#pragma unroll 4
            for (int k = 0; k < 64; ++k) {
                const float* ap = &sT[k * 68 + ti * 8];
                float4 alo = *(const float4*)ap;
                float4 ahi = *(const float4*)(ap + 4);
                uint2 wu = *(const uint2*)&Wlu[(ch * 64 + k) * 32 + (cw >> 1)];
                float a8[8] = {alo.x, alo.y, alo.z, alo.w, ahi.x, ahi.y, ahi.z, ahi.w};
                float w4[4] = {ulo(wu.x), uhi(wu.x), ulo(wu.y), uhi(wu.y)};
#pragma unroll
                for (int i = 0; i < 8; ++i)
#pragma unroll
                    for (int j = 0; j < 4; ++j) acc[i][j] += a8[i] * w4[j];
            }
        }
    }
    if (tid >= 128) return;

    float4 bv = *(const float4*)&bt[cw];
    float bj[4] = {bv.x, bv.y, bv.z, bv.w};

    float s4[4] = {0.f, 0.f, 0.f, 0.f}, q4[4] = {0.f, 0.f, 0.f, 0.f};
    uint2* hB2 = (uint2*)hB;
#pragma unroll
    for (int i = 0; i < 8; ++i) {
        int n = base + ti * 8 + i;
        if (n < NND) {
            float o[4];
#pragma unroll
            for (int j = 0; j < 4; ++j) {
                o[j] = acc[i][j] + bj[j];
                s4[j] += o[j];
                q4[j] += o[j] * o[j];
            }
            uint2 ov; ov.x = pk(o[0], o[1]); ov.y = pk(o[2], o[3]);
            hB2[((size_t)wave * NND + n) * 8 + tj] = ov;   // column-split write
        }
    }
#pragma unroll
    for (int m = 1; m < 8; m <<= 1) {
#pragma unroll
        for (int j = 0; j < 4; ++j) {
            s4[j] += __shfl_xor(s4[j], m);
            q4[j] += __shfl_xor(q4[j], m);
        }
    }
    if (ti == 0) {
        int slot = (tile & (NCOPY - 1)) * 128;
#pragma unroll
        for (int j = 0; j < 4; ++j) {
            atomicAdd(&stats[slot + cw + j], s4[j]);
            atomicAdd(&stats[slot + 64 + cw + j], q4[j]);
        }
    }
}

// ---------------- CSR fill (R15): batch all 8 stream loads up-front ----------------
__global__ __launch_bounds__(256) void k_fill(const int* __restrict__ src,
                                              const int* __restrict__ dst,
                                              int* __restrict__ cur,
                                              int* __restrict__ esrc) {
    int xcd = blockIdx.x & 7;
    int chunk = blockIdx.x >> 3;
    int lo = xcd * XNODES;
    const int4* d4 = (const int4*)dst;
    const int4* s4 = (const int4*)src;
    int4 d[4], s[4];
#pragma unroll
    for (int r = 0; r < 4; ++r) {
        int i = chunk * 1024 + r * 256 + threadIdx.x;
        int ii = i < NE4 ? i : NE4 - 1;
        d[r] = d4[ii];
        s[r] = s4[ii];
        if (i >= NE4) d[r] = make_int4(-1, -1, -1, -1);
    }
#pragma unroll
    for (int r = 0; r < 4; ++r) {
        if ((unsigned)(d[r].x - lo) < XNODES) esrc[atomicAdd(&cur[d[r].x], 1)] = s[r].x;
        if ((unsigned)(d[r].y - lo) < XNODES) esrc[atomicAdd(&cur[d[r].y], 1)] = s[r].y;
        if ((unsigned)(d[r].z - lo) < XNODES) esrc[atomicAdd(&cur[d[r].z], 1)] = s[r].z;
        if ((unsigned)(d[r].w - lo) < XNODES) esrc[atomicAdd(&cur[d[r].w], 1)] = s[r].w;
    }
}

__global__ __launch_bounds__(SCB) void k_part(const int* __restrict__ deg,
                                              int* __restrict__ offs,
                                              int* __restrict__ parts) {
    __shared__ int sd[SCB];
    int t = threadIdx.x;
    int i = blockIdx.x * SCB + t;
    int v = (i < NND) ? deg[i] : 0;
    sd[t] = v;
    __syncthreads();
#pragma unroll
    for (int off = 1; off < SCB; off <<= 1) {
        int u = (t >= off) ? sd[t - off] : 0;
        __syncthreads();
        sd[t] += u;
        __syncthreads();
    }
    if (i < NND) offs[i] = sd[t] - v;
    if (t == SCB - 1) parts[blockIdx.x] = sd[t];
}

__global__ __launch_bounds__(256) void k_apply(int* __restrict__ offs,
                                               const int* __restrict__ parts,
                                               int* __restrict__ cur) {
    __shared__ int sd[256];
    int t = threadIdx.x;
    int v = (t < NSB) ? parts[t] : 0;
    sd[t] = v;
    __syncthreads();
#pragma unroll
    for (int off = 1; off < 256; off <<= 1) {
        int u = (t >= off) ? sd[t - off] : 0;
        __syncthreads();
        sd[t] += u;
        __syncthreads();
    }
    int c = blockIdx.x;
    int add = sd[c] - parts[c];
    int i = blockIdx.x * 256 + t;
    if (i < NND) {
        int o = offs[i] + add;
        offs[i] = o;
        cur[i] = o;
    }
    if (i == NND) offs[NND] = NED;
}

// ---------------- aggregation: one column-half per launch (3.2MB table -> L2-resident) ----
// wave = node; 4 lanes x 16B cover the 64B row-half; 16 edge slots.
__global__ __launch_bounds__(256) void k_agg(const uint4* __restrict__ hB4,
                                             uint4* __restrict__ aggB4,
                                             const float* __restrict__ stats,
                                             const float* __restrict__ g,
                                             const float* __restrict__ b,
                                             const int* __restrict__ offs,
                                             const int* __restrict__ esrc,
                                             int half) {
    int tid  = threadIdx.x;
    int lane = tid & 63;
    int wv   = tid >> 6;
    int n = blockIdx.x * 4 + wv;
    int q = lane & 3;        // 16B chunk within 64B row-half
    int r = lane >> 2;       // edge slot 0..15
    size_t hbase = (size_t)half * NND;

    // lane derives BN for global col half*32 + (lane&31)
    float scl, shl;
    bn_derive(stats, half * 32 + (lane & 31), g, b, scl, shl);

    int e0 = offs[n], e1 = offs[n + 1];
    int deg = e1 - e0;

    float a[8];
#pragma unroll
    for (int i = 0; i < 8; ++i) a[i] = 0.f;

    if (r == 0) {            // self row-half: 4 lanes x 16B
        uint4 u = hB4[(hbase + n) * 4 + q];
        upadd(u.x, a[0], a[1]); upadd(u.y, a[2], a[3]);
        upadd(u.z, a[4], a[5]); upadd(u.w, a[6], a[7]);
    }

    for (int bb = e0; bb < e1; bb += 64) {
        int m = e1 - bb; if (m > 64) m = 64;
        int idx = (lane < m) ? esrc[bb + lane] : 0;
        int ng = (m + 15) >> 4;           // wave-uniform group count (16 edges/group)
        uint4 u[4];
#pragma unroll
        for (int gI = 0; gI < 4; ++gI) {
            if (gI < ng) {
                int e = gI * 16 + r;
                int j = __shfl(idx, e & 63);
                u[gI] = make_uint4(0u, 0u, 0u, 0u);
                if (e < m) u[gI] = hB4[(hbase + j) * 4 + q];
            }
        }
#pragma unroll
        for (int gI = 0; gI < 4; ++gI) {
            if (gI < ng) {
                upadd(u[gI].x, a[0], a[1]); upadd(u[gI].y, a[2], a[3]);
                upadd(u[gI].z, a[4], a[5]); upadd(u[gI].w, a[6], a[7]);
            }
        }
    }

    // reduce across the 16 edge slots (lane bits 2..5); q preserved
#pragma unroll
    for (int msk = 4; msk <= 32; msk <<= 1)
#pragma unroll
        for (int i = 0; i < 8; ++i) a[i] += __shfl_xor(a[i], msk);

    // gather (sc,sh) for this lane's 8 columns: local cols q*8..q*8+7 (held by lanes q*8+j)
    float sc8[8], sh8[8];
#pragma unroll
    for (int j = 0; j < 8; ++j) {
        sc8[j] = __shfl(scl, q * 8 + j);
        sh8[j] = __shfl(shl, q * 8 + j);
    }

    if (r == 0) {
        float dn = (float)(deg + 1);
        float o[8];
#pragma unroll
        for (int j = 0; j < 8; ++j) o[j] = sc8[j] * a[j] + dn * sh8[j];
        uint4 ov;
        ov.x = pk(o[0], o[1]); ov.y = pk(o[2], o[3]);
        ov.z = pk(o[4], o[5]); ov.w = pk(o[6], o[7]);
        aggB4[(hbase + n) * 4 + q] = ov;
    }
}

// ---------------- MLP: col-split 1-tile blocks (2 waves, acc 8x4), 2 GEMMs ----------------
__global__ __launch_bounds__(128) void k_mlp(const uint4* __restrict__ aggB4,
                                             float* __restrict__ outF,    // f32 out (last layer) or null
                                             unsigned* __restrict__ hBo,  // bf16 out (col-split) or null
                                             float* __restrict__ stats,
                                             const float* __restrict__ W1,
                                             const float* __restrict__ W2) {
    __shared__ __align__(16) float W1l[NH * NH];
    __shared__ __align__(16) float W2l[NH * NH];
    __shared__ __align__(16) float sT[64 * 68];
    int tid  = threadIdx.x;
    int wave = tid >> 6, lane = tid & 63;
    int ti = lane & 7, tj = lane >> 3;
    int tile = blockIdx.x;
    int base = tile * 64;
    int cw = wave * 32 + tj * 4;

#pragma unroll
    for (int r = 0; r < 8; ++r) {
        int i4 = r * 128 + tid;
        ((float4*)W1l)[i4] = ((const float4*)W1)[i4];
        ((float4*)W2l)[i4] = ((const float4*)W2)[i4];
    }
    // stage agg tile transposed from the column-split layout
#pragma unroll
    for (int s = 0; s < 4; ++s) {
        int i4 = s * 128 + tid;           // 0..511
        int nl = i4 >> 3, z = i4 & 7;
        int h = z >> 2, qq = z & 3;
        uint4 u = make_uint4(0u, 0u, 0u, 0u);
        if (base + nl < NND) u = aggB4[((size_t)h * NND + base + nl) * 4 + qq];
        int c0 = h * 32 + qq * 8;
        sT[(c0 + 0) * 68 + nl] = ulo(u.x);
        sT[(c0 + 1) * 68 + nl] = uhi(u.x);
        sT[(c0 + 2) * 68 + nl] = ulo(u.y);
        sT[(c0 + 3) * 68 + nl] = uhi(u.y);
        sT[(c0 + 4) * 68 + nl] = ulo(u.z);
        sT[(c0 + 5) * 68 + nl] = uhi(u.z);
        sT[(c0 + 6) * 68 + nl] = ulo(u.w);
        sT[(c0 + 7) * 68 + nl] = uhi(u.w);
    }
    __syncthreads();

    float a1[8][4];
#pragma unroll
    for (int i = 0; i < 8; ++i)
#pragma unroll
        for (int j = 0; j < 4; ++j) a1[i][j] = 0.f;
#pragma unroll 4
    for (int k = 0; k < 64; ++k) {
        const float* ap = &sT[k * 68 + ti * 8];
        float4 alo = *(const float4*)ap;
        float4 ahi = *(const float4*)(ap + 4);
        float4 wv  = *(const float4*)&W1l[k * NH + cw];
        float a8[8] = {alo.x, alo.y, alo.z, alo.w, ahi.x, ahi.y, ahi.z, ahi.w};
        float w4[4] = {wv.x, wv.y, wv.z, wv.w};
#pragma unroll
        for (int i = 0; i < 8; ++i)
#pragma unroll
            for (int j = 0; j < 4; ++j) a1[i][j] += a8[i] * w4[j];
    }
#pragma unroll
    for (int i = 0; i < 8; ++i)
#pragma unroll
        for (int j = 0; j < 4; ++j) a1[i][j] = fmaxf(a1[i][j], 0.f);

    __syncthreads();
#pragma unroll
    for (int j = 0; j < 4; ++j) {
        float* p = &sT[(cw + j) * 68 + ti * 8];
        float4 lo = {a1[0][j], a1[1][j], a1[2][j], a1[3][j]};
        float4 hi = {a1[4][j], a1[5][j], a1[6][j], a1[7][j]};
        *(float4*)p = lo;
        *(float4*)(p + 4) = hi;
    }
    __syncthreads();

    float a2[8][4];
#pragma unroll
    for (int i = 0; i < 8; ++i)
#pragma unroll
        for (int j = 0; j < 4; ++j) a2[i][j] = 0.f;
#pragma unroll 4
    for (int k = 0; k < 64; ++k) {
        const float* ap = &sT[k * 68 + ti * 8];
        float4 alo = *(const float4*)ap;
        float4 ahi = *(const float4*)(ap + 4);
        float4 wv  = *(const float4*)&W2l[k * NH + cw];
        float a8[8] = {alo.x, alo.y, alo.z, alo.w, ahi.x, ahi.y, ahi.z, ahi.w};
        float w4[4] = {wv.x, wv.y, wv.z, wv.w};
#pragma unroll
        for (int i = 0; i < 8; ++i)
#pragma unroll
            for (int j = 0; j < 4; ++j) a2[i][j] += a8[i] * w4[j];
    }

    float s4[4] = {0.f, 0.f, 0.f, 0.f}, q4[4] = {0.f, 0.f, 0.f, 0.f};
    uint2* hBo2 = (uint2*)hBo;
#pragma unroll
    for (int i = 0; i < 8; ++i) {
        int n = base + ti * 8 + i;
        if (n < NND) {
            float o[4];
#pragma unroll
            for (int j = 0; j < 4; ++j) {
                o[j] = fmaxf(a2[i][j], 0.f);
                s4[j] += o[j];
                q4[j] += o[j] * o[j];
            }
            if (outF) *(float4*)&outF[(size_t)n * NH + cw] = *(float4*)&o[0];
            if (hBo) {
                uint2 ov; ov.x = pk(o[0], o[1]); ov.y = pk(o[2], o[3]);
                hBo2[((size_t)wave * NND + n) * 8 + tj] = ov;   // column-split write
            }
        }
    }
#pragma unroll
    for (int m = 1; m < 8; m <<= 1) {
#pragma unroll
        for (int j = 0; j < 4; ++j) {
            s4[j] += __shfl_xor(s4[j], m);
            q4[j] += __shfl_xor(q4[j], m);
        }
    }
    if (ti == 0) {
        int slot = (tile & (NCOPY - 1)) * 128;
#pragma unroll
        for (int j = 0; j < 4; ++j) {
            atomicAdd(&stats[slot + cw + j], s4[j]);
            atomicAdd(&stats[slot + 64 + cw + j], q4[j]);
        }
    }
}

// ---------------- final BN apply, in-place on f32 out ----------------
__global__ __launch_bounds__(256) void k_bnout(float* __restrict__ h,
                                               const float* __restrict__ stats,
                                               const float* __restrict__ g,
                                               const float* __restrict__ b) {
    __shared__ float sl[128];
    int tid = threadIdx.x;
    if (tid < 64) {
        float sc, sh;
        bn_derive(stats, tid, g, b, sc, sh);
        sl[tid]      = sc;
        sl[64 + tid] = sh;
    }
    __syncthreads();
    int i4 = blockIdx.x * 256 + tid;
    if (i4 < NND * NH / 4) {
        int cg = i4 & 15;
        float4 v   = ((float4*)h)[i4];
        float4 scv = *(float4*)&sl[cg * 4];
        float4 shv = *(float4*)&sl[64 + cg * 4];
        v.x = v.x * scv.x + shv.x;
        v.y = v.y * scv.y + shv.y;
        v.z = v.z * scv.z + shv.z;
        v.w = v.w * scv.w + shv.w;
        ((float4*)h)[i4] = v;
    }
}

extern "C" void kernel_launch(void* const* d_in, const int* in_sizes, int n_in,
                              void* d_out, int out_size, void* d_ws, size_t ws_size,
                              hipStream_t stream) {
    const float* x     = (const float*)d_in[0];
    const int*   ei    = (const int*)d_in[1];
    const float* Wt    = (const float*)d_in[2];
    const float* bt    = (const float*)d_in[3];
    const float* gt    = (const float*)d_in[4];
    const float* bbt   = (const float*)d_in[5];
    const float* W1    = (const float*)d_in[6];
    const float* W2    = (const float*)d_in[7];
    const float* gamma = (const float*)d_in[8];
    const float* beta  = (const float*)d_in[9];
    float* out = (float*)d_out;

    char* ws = (char*)d_ws;
    unsigned* hB    = (unsigned*)(ws + WS_HB);
    unsigned* aggB  = (unsigned*)(ws + WS_AGG);
    float*    stats = (float*)(ws + WS_STATS);
    int*      deg   = (int*)(ws + WS_DEG);
    int*      offs  = (int*)(ws + WS_OFFS);
    int*      cur   = (int*)(ws + WS_CUR);
    int*      parts = (int*)(ws + WS_PARTS);
    int*      esrc  = (int*)(ws + WS_ESRC);

    float* st0 = stats;
    float* st1 = stats + NCOPY * 128;
    float* st2 = stats + 2 * NCOPY * 128;
    float* st3 = stats + 3 * NCOPY * 128;

    const int* srcv = ei;
    const int* dstv = ei + NED;

    // one memset covers all 4 stat buffers + deg (contiguous)
    hipMemsetAsync(stats, 0, 4 * NCOPY * 128 * 4 + NND * 4, stream);

    // fused transform || degree count
    k_dtf<<<NT + PGRID, 256, 0, stream>>>(dstv, deg, x, Wt, bt, hB, st0);
    k_part<<<NSB, SCB, 0, stream>>>(deg, offs, parts);
    k_apply<<<NSB, 256, 0, stream>>>(offs, parts, cur);
    k_fill<<<PGRID, 256, 0, stream>>>(srcv, dstv, cur, esrc);

    const int NB = NND / 4;         // 12500 agg blocks per half

    // layer 0: two sequential half-kernels (each half's 3.2MB table L2-resident)
    k_agg<<<NB, 256, 0, stream>>>((const uint4*)hB, (uint4*)aggB, st0, gt, bbt, offs, esrc, 0);
    k_agg<<<NB, 256, 0, stream>>>((const uint4*)hB, (uint4*)aggB, st0, gt, bbt, offs, esrc, 1);
    k_mlp<<<NT, 128, 0, stream>>>((const uint4*)aggB, nullptr, hB, st1, W1, W2);

    // layer 1
    k_agg<<<NB, 256, 0, stream>>>((const uint4*)hB, (uint4*)aggB, st1, gamma, beta, offs, esrc, 0);
    k_agg<<<NB, 256, 0, stream>>>((const uint4*)hB, (uint4*)aggB, st1, gamma, beta, offs, esrc, 1);
    k_mlp<<<NT, 128, 0, stream>>>((const uint4*)aggB, nullptr, hB, st2, W1 + 4096, W2 + 4096);

    // layer 2: f32 out for final BN
    k_agg<<<NB, 256, 0, stream>>>((const uint4*)hB, (uint4*)aggB, st2, gamma + 64, beta + 64, offs, esrc, 0);
    k_agg<<<NB, 256, 0, stream>>>((const uint4*)hB, (uint4*)aggB, st2, gamma + 64, beta + 64, offs, esrc, 1);
    k_mlp<<<NT, 128, 0, stream>>>((const uint4*)aggB, out, nullptr, st3, W1 + 8192, W2 + 8192);

    k_bnout<<<(NND * NH / 4 + 255) / 256, 256, 0, stream>>>(out, st3, gamma + 128, beta + 128);
}

// Round 20
// 302.055 us; speedup vs baseline: 1.2660x; 1.2660x over previous
//
#include <hip/hip_runtime.h>

#define NND 50000
#define NED 800000
#define NF  128
#define NH  64
#define BN_EPS 1e-5
#define NCOPY 8    // stats slot-copies (f32)
#define SCB  256   // scan chunk
#define NSB  ((NND + SCB - 1) / SCB)   // 196 scan blocks
#define XNODES (NND / 8)               // 6250 nodes per XCD slice
#define FCH  196                       // edge chunks (1024 int4 each) per XCD pass
#define NT   782                       // transform/mlp tiles
#define PGRID (FCH * 8)                // 1568 edge-partition blocks
#define NE4  (NED / 4)                 // 200000 int4 edge quads

// ---- workspace byte offsets (16B aligned) ----
#define WS_HB     0                          // bf16[NND*64]  (h, gather source)   6,400,000 B
#define WS_AGG    6400000                    // bf16[NND*64]  (agg, MLP input)     6,400,000 B
#define WS_STATS  12800000                   // float[4][NCOPY*128] = 16 KB (4 stages, memset each call)
#define WS_DEG    (WS_STATS + 4*NCOPY*128*4) // int[NND]  (memset'd with stats)
#define WS_OFFS   (WS_DEG + NND*4)           // int[NND+4]
#define WS_CUR    (WS_OFFS + (NND+4)*4)      // int[NND]
#define WS_PARTS  (WS_CUR + NND*4)           // int[256]
#define WS_ESRC   (WS_PARTS + 256*4)         // int[NED]

// ---- bf16 helpers (storage-only; all math in f32) ----
__device__ __forceinline__ unsigned bfrn(float x) {          // f32 -> bf16 (RTN-even)
    unsigned u = __float_as_uint(x);
    return (u + 0x7fffu + ((u >> 16) & 1u)) >> 16;
}
__device__ __forceinline__ unsigned pk(float lo, float hi) { // 2x f32 -> packed bf16x2
    return bfrn(lo) | (bfrn(hi) << 16);
}
__device__ __forceinline__ float ulo(unsigned u) { return __uint_as_float(u << 16); }
__device__ __forceinline__ float uhi(unsigned u) { return __uint_as_float(u & 0xffff0000u); }
__device__ __forceinline__ void upadd(unsigned u, float& lo, float& hi) {
    lo += ulo(u); hi += uhi(u);
}

// derive BN scale/shift for column c from f32 slot-copy stats
__device__ __forceinline__ void bn_derive(const float* __restrict__ st, int c,
                                          const float* __restrict__ g,
                                          const float* __restrict__ b,
                                          float& sc, float& sh) {
    float sum = 0.f, ssq = 0.f;
#pragma unroll
    for (int cp = 0; cp < NCOPY; ++cp) {
        sum += st[cp * 128 + c];
        ssq += st[cp * 128 + 64 + c];
    }
    double mu  = (double)sum / (double)NND;
    double var = (double)ssq / (double)NND - mu * mu;
    if (var < 0.0) var = 0.0;
    double rs = 1.0 / sqrt(var + BN_EPS);
    double scd = (double)g[c] * rs;
    sc = (float)scd;
    sh = (float)((double)b[c] - mu * scd);
}

// ---------------- FUSED: transform (blocks [0,NT)) || degree count (blocks [NT,NT+PGRID)) ----
__global__ __launch_bounds__(256) void k_dtf(const int* __restrict__ dst,
                                             int* __restrict__ deg,
                                             const float* __restrict__ x,
                                             const float* __restrict__ Wt,
                                             const float* __restrict__ bt,
                                             unsigned* __restrict__ hB,
                                             float* __restrict__ stats) {
    __shared__ __align__(16) unsigned Wlu[NF * NH / 2]; // 16 KB, bf16-packed
    __shared__ __align__(16) float sT[64 * 68];         // 17.4 KB
    int tid = threadIdx.x;

    if (blockIdx.x >= NT) {
        // ---- degree-count body: batch all 4 stream loads up-front (ILP) ----
        int dbid = blockIdx.x - NT;
        int xcd = dbid & 7;
        int chunk = dbid >> 3;
        int lo = xcd * XNODES;
        const int4* d4 = (const int4*)dst;
        int4 d[4];
#pragma unroll
        for (int r = 0; r < 4; ++r) {
            int i = chunk * 1024 + r * 256 + tid;
            int ii = i < NE4 ? i : NE4 - 1;
            d[r] = d4[ii];
            if (i >= NE4) d[r] = make_int4(-1, -1, -1, -1);
        }
#pragma unroll
        for (int r = 0; r < 4; ++r) {
            if ((unsigned)(d[r].x - lo) < XNODES) atomicAdd(&deg[d[r].x], 1);
            if ((unsigned)(d[r].y - lo) < XNODES) atomicAdd(&deg[d[r].y], 1);
            if ((unsigned)(d[r].z - lo) < XNODES) atomicAdd(&deg[d[r].z], 1);
            if ((unsigned)(d[r].w - lo) < XNODES) atomicAdd(&deg[d[r].w], 1);
        }
        return;
    }

    // ---- transform body: one 64-node tile; all 256 threads stage, waves 0-1 compute ----
    int tile = blockIdx.x;
    int base = tile * 64;
    const float4* x4 = (const float4*)x;

#pragma unroll
    for (int r = 0; r < 8; ++r) {
        int i4 = r * 256 + tid;
        float4 w = ((const float4*)Wt)[i4];
        uint2 wp; wp.x = pk(w.x, w.y); wp.y = pk(w.z, w.w);
        ((uint2*)Wlu)[i4] = wp;
    }

    int wave = tid >> 6, lane = tid & 63;
    int ti = lane & 7, tj = lane >> 3;
    int cw = wave * 32 + tj * 4;          // compute waves 0-1: output cols

    float acc[8][4];
#pragma unroll
    for (int i = 0; i < 8; ++i)
#pragma unroll
        for (int j = 0; j < 4; ++j) acc[i][j] = 0.f;

    for (int ch = 0; ch < 2; ++ch) {
        __syncthreads();
        float4 pf[4];
#pragma unroll
        for (int s = 0; s < 4; ++s) {
            int flat = s * 256 + tid;
            int nl = flat >> 4, q = flat & 15;
            pf[s] = make_float4(0.f, 0.f, 0.f, 0.f);
            if (base + nl < NND) pf[s] = x4[(size_t)(base + nl) * 32 + ch * 16 + q];
        }
#pragma unroll
        for (int s = 0; s < 4; ++s) {
            int flat = s * 256 + tid;
            int nl = flat >> 4, q = flat & 15;
            sT[(q * 4 + 0) * 68 + nl] = pf[s].x;
            sT[(q * 4 + 1) * 68 + nl] = pf[s].y;
            sT[(q * 4 + 2) * 68 + nl] = pf[s].z;
            sT[(q * 4 + 3) * 68 + nl] = pf[s].w;
        }
        __syncthreads();
        if (tid < 128) {
#pragma unroll 4
            for (int k = 0; k < 64; ++k) {
                const float* ap = &sT[k * 68 + ti * 8];
                float4 alo = *(const float4*)ap;
                float4 ahi = *(const float4*)(ap + 4);
                uint2 wu = *(const uint2*)&Wlu[(ch * 64 + k) * 32 + (cw >> 1)];
                float a8[8] = {alo.x, alo.y, alo.z, alo.w, ahi.x, ahi.y, ahi.z, ahi.w};
                float w4[4] = {ulo(wu.x), uhi(wu.x), ulo(wu.y), uhi(wu.y)};
#pragma unroll
                for (int i = 0; i < 8; ++i)
#pragma unroll
                    for (int j = 0; j < 4; ++j) acc[i][j] += a8[i] * w4[j];
            }
        }
    }
    if (tid >= 128) return;

    float4 bv = *(const float4*)&bt[cw];
    float bj[4] = {bv.x, bv.y, bv.z, bv.w};

    float s4[4] = {0.f, 0.f, 0.f, 0.f}, q4[4] = {0.f, 0.f, 0.f, 0.f};
    uint2* hB2 = (uint2*)hB;
#pragma unroll
    for (int i = 0; i < 8; ++i) {
        int n = base + ti * 8 + i;
        if (n < NND) {
            float o[4];
#pragma unroll
            for (int j = 0; j < 4; ++j) {
                o[j] = acc[i][j] + bj[j];
                s4[j] += o[j];
                q4[j] += o[j] * o[j];
            }
            uint2 ov; ov.x = pk(o[0], o[1]); ov.y = pk(o[2], o[3]);
            hB2[(size_t)n * 16 + wave * 8 + tj] = ov;
        }
    }
#pragma unroll
    for (int m = 1; m < 8; m <<= 1) {
#pragma unroll
        for (int j = 0; j < 4; ++j) {
            s4[j] += __shfl_xor(s4[j], m);
            q4[j] += __shfl_xor(q4[j], m);
        }
    }
    if (ti == 0) {
        int slot = (tile & (NCOPY - 1)) * 128;
#pragma unroll
        for (int j = 0; j < 4; ++j) {
            atomicAdd(&stats[slot + cw + j], s4[j]);
            atomicAdd(&stats[slot + 64 + cw + j], q4[j]);
        }
    }
}

// ---------------- CSR fill: batch all 8 stream loads up-front (ILP) ----------------
__global__ __launch_bounds__(256) void k_fill(const int* __restrict__ src,
                                              const int* __restrict__ dst,
                                              int* __restrict__ cur,
                                              int* __restrict__ esrc) {
    int xcd = blockIdx.x & 7;
    int chunk = blockIdx.x >> 3;
    int lo = xcd * XNODES;
    const int4* d4 = (const int4*)dst;
    const int4* s4 = (const int4*)src;
    int4 d[4], s[4];
#pragma unroll
    for (int r = 0; r < 4; ++r) {
        int i = chunk * 1024 + r * 256 + threadIdx.x;
        int ii = i < NE4 ? i : NE4 - 1;
        d[r] = d4[ii];
        s[r] = s4[ii];
        if (i >= NE4) d[r] = make_int4(-1, -1, -1, -1);
    }
#pragma unroll
    for (int r = 0; r < 4; ++r) {
        if ((unsigned)(d[r].x - lo) < XNODES) esrc[atomicAdd(&cur[d[r].x], 1)] = s[r].x;
        if ((unsigned)(d[r].y - lo) < XNODES) esrc[atomicAdd(&cur[d[r].y], 1)] = s[r].y;
        if ((unsigned)(d[r].z - lo) < XNODES) esrc[atomicAdd(&cur[d[r].z], 1)] = s[r].z;
        if ((unsigned)(d[r].w - lo) < XNODES) esrc[atomicAdd(&cur[d[r].w], 1)] = s[r].w;
    }
}

// pass 1: per-256-chunk exclusive scan into offs, chunk totals into parts
__global__ __launch_bounds__(SCB) void k_part(const int* __restrict__ deg,
                                              int* __restrict__ offs,
                                              int* __restrict__ parts) {
    __shared__ int sd[SCB];
    int t = threadIdx.x;
    int i = blockIdx.x * SCB + t;
    int v = (i < NND) ? deg[i] : 0;
    sd[t] = v;
    __syncthreads();
#pragma unroll
    for (int off = 1; off < SCB; off <<= 1) {
        int u = (t >= off) ? sd[t - off] : 0;
        __syncthreads();
        sd[t] += u;
        __syncthreads();
    }
    if (i < NND) offs[i] = sd[t] - v;
    if (t == SCB - 1) parts[blockIdx.x] = sd[t];
}

// pass 2 (merged): each block redundantly scans the 196 partials in LDS,
// applies its chunk offset, writes cur.
__global__ __launch_bounds__(256) void k_apply(int* __restrict__ offs,
                                               const int* __restrict__ parts,
                                               int* __restrict__ cur) {
    __shared__ int sd[256];
    int t = threadIdx.x;
    int v = (t < NSB) ? parts[t] : 0;
    sd[t] = v;
    __syncthreads();
#pragma unroll
    for (int off = 1; off < 256; off <<= 1) {
        int u = (t >= off) ? sd[t - off] : 0;
        __syncthreads();
        sd[t] += u;
        __syncthreads();
    }
    int c = blockIdx.x;
    int add = sd[c] - parts[c];   // exclusive prefix for this chunk
    int i = blockIdx.x * 256 + t;
    if (i < NND) {
        int o = offs[i] + add;
        offs[i] = o;
        cur[i] = o;
    }
    if (i == NND) offs[NND] = NED;
}

// ---------------- aggregation: wave-per-node, bf16 rows, 8 slots (R13/R15 known-good) ----------------
__global__ __launch_bounds__(256) void k_agg(const uint4* __restrict__ hB4,
                                             uint4* __restrict__ aggB4,
                                             const float* __restrict__ stats,
                                             const float* __restrict__ g,
                                             const float* __restrict__ b,
                                             const int* __restrict__ offs,
                                             const int* __restrict__ esrc) {
    int tid  = threadIdx.x;
    int lane = tid & 63;
    int wv   = tid >> 6;
    int n = blockIdx.x * 4 + wv;
    int q = lane & 7;        // 16B sub-block within 128B row
    int r = lane >> 3;       // edge slot 0..7

    // per-lane BN derive for column `lane` (L2-hot 4KB)
    float scl, shl;
    bn_derive(stats, lane, g, b, scl, shl);

    int e0 = offs[n], e1 = offs[n + 1];
    int deg = e1 - e0;

    float a[8];
#pragma unroll
    for (int i = 0; i < 8; ++i) a[i] = 0.f;

    if (r == 0) {
        uint4 u = hB4[(size_t)n * 8 + q];
        upadd(u.x, a[0], a[1]); upadd(u.y, a[2], a[3]);
        upadd(u.z, a[4], a[5]); upadd(u.w, a[6], a[7]);
    }

    for (int bb = e0; bb < e1; bb += 64) {
        int m = e1 - bb; if (m > 64) m = 64;
        int idx = (lane < m) ? esrc[bb + lane] : 0;
        int t = 0;
        for (; t + 32 <= m; t += 32) {
            int j0 = __shfl(idx, t + r);
            int j1 = __shfl(idx, t + 8 + r);
            int j2 = __shfl(idx, t + 16 + r);
            int j3 = __shfl(idx, t + 24 + r);
            uint4 u0 = hB4[(size_t)j0 * 8 + q];
            uint4 u1 = hB4[(size_t)j1 * 8 + q];
            uint4 u2 = hB4[(size_t)j2 * 8 + q];
            uint4 u3 = hB4[(size_t)j3 * 8 + q];
            upadd(u0.x, a[0], a[1]); upadd(u0.y, a[2], a[3]);
            upadd(u0.z, a[4], a[5]); upadd(u0.w, a[6], a[7]);
            upadd(u1.x, a[0], a[1]); upadd(u1.y, a[2], a[3]);
            upadd(u1.z, a[4], a[5]); upadd(u1.w, a[6], a[7]);
            upadd(u2.x, a[0], a[1]); upadd(u2.y, a[2], a[3]);
            upadd(u2.z, a[4], a[5]); upadd(u2.w, a[6], a[7]);
            upadd(u3.x, a[0], a[1]); upadd(u3.y, a[2], a[3]);
            upadd(u3.z, a[4], a[5]); upadd(u3.w, a[6], a[7]);
        }
        for (; t < m; t += 8) {
            int e = t + r;
            int j = __shfl(idx, e & 63);
            if (e < m) {
                uint4 u = hB4[(size_t)j * 8 + q];
                upadd(u.x, a[0], a[1]); upadd(u.y, a[2], a[3]);
                upadd(u.z, a[4], a[5]); upadd(u.w, a[6], a[7]);
            }
        }
    }

#pragma unroll
    for (int msk = 8; msk <= 32; msk <<= 1)
#pragma unroll
        for (int i = 0; i < 8; ++i) a[i] += __shfl_xor(a[i], msk);

    // gather the 8 (sc,sh) pairs for this lane's columns q*8..q*8+7
    float sc8[8], sh8[8];
#pragma unroll
    for (int j = 0; j < 8; ++j) {
        sc8[j] = __shfl(scl, q * 8 + j);
        sh8[j] = __shfl(shl, q * 8 + j);
    }

    if (r == 0) {
        float dn = (float)(deg + 1);
        float o[8];
#pragma unroll
        for (int j = 0; j < 8; ++j) o[j] = sc8[j] * a[j] + dn * sh8[j];
        uint4 ov;
        ov.x = pk(o[0], o[1]); ov.y = pk(o[2], o[3]);
        ov.z = pk(o[4], o[5]); ov.w = pk(o[6], o[7]);
        aggB4[(size_t)n * 8 + q] = ov;
    }
}

// ---------------- MLP: col-split 1-tile blocks (2 waves, acc 8x4), 2 GEMMs ----------------
__global__ __launch_bounds__(128) void k_mlp(const uint4* __restrict__ aggB4,
                                             float* __restrict__ outF,    // f32 out (last layer) or null
                                             unsigned* __restrict__ hBo,  // bf16 out or null
                                             float* __restrict__ stats,
                                             const float* __restrict__ W1,
                                             const float* __restrict__ W2) {
    __shared__ __align__(16) float W1l[NH * NH];  // 16 KB
    __shared__ __align__(16) float W2l[NH * NH];  // 16 KB
    __shared__ __align__(16) float sT[64 * 68];   // 17.4 KB (agg, then t1)
    int tid  = threadIdx.x;
    int wave = tid >> 6, lane = tid & 63;
    int ti = lane & 7, tj = lane >> 3;
    int tile = blockIdx.x;
    int base = tile * 64;
    int cw = wave * 32 + tj * 4;

#pragma unroll
    for (int r = 0; r < 8; ++r) {
        int i4 = r * 128 + tid;
        ((float4*)W1l)[i4] = ((const float4*)W1)[i4];
        ((float4*)W2l)[i4] = ((const float4*)W2)[i4];
    }
#pragma unroll
    for (int s = 0; s < 4; ++s) {
        int i4 = s * 128 + tid;
        int nl = i4 >> 3, q = i4 & 7;
        uint4 u = make_uint4(0u, 0u, 0u, 0u);
        if (base + nl < NND) u = aggB4[(size_t)(base + nl) * 8 + q];
        sT[(q * 8 + 0) * 68 + nl] = ulo(u.x);
        sT[(q * 8 + 1) * 68 + nl] = uhi(u.x);
        sT[(q * 8 + 2) * 68 + nl] = ulo(u.y);
        sT[(q * 8 + 3) * 68 + nl] = uhi(u.y);
        sT[(q * 8 + 4) * 68 + nl] = ulo(u.z);
        sT[(q * 8 + 5) * 68 + nl] = uhi(u.z);
        sT[(q * 8 + 6) * 68 + nl] = ulo(u.w);
        sT[(q * 8 + 7) * 68 + nl] = uhi(u.w);
    }
    __syncthreads();

    float a1[8][4];
#pragma unroll
    for (int i = 0; i < 8; ++i)
#pragma unroll
        for (int j = 0; j < 4; ++j) a1[i][j] = 0.f;
#pragma unroll 4
    for (int k = 0; k < 64; ++k) {
        const float* ap = &sT[k * 68 + ti * 8];
        float4 alo = *(const float4*)ap;
        float4 ahi = *(const float4*)(ap + 4);
        float4 wv  = *(const float4*)&W1l[k * NH + cw];
        float a8[8] = {alo.x, alo.y, alo.z, alo.w, ahi.x, ahi.y, ahi.z, ahi.w};
        float w4[4] = {wv.x, wv.y, wv.z, wv.w};
#pragma unroll
        for (int i = 0; i < 8; ++i)
#pragma unroll
            for (int j = 0; j < 4; ++j) a1[i][j] += a8[i] * w4[j];
    }
#pragma unroll
    for (int i = 0; i < 8; ++i)
#pragma unroll
        for (int j = 0; j < 4; ++j) a1[i][j] = fmaxf(a1[i][j], 0.f);

    __syncthreads();
#pragma unroll
    for (int j = 0; j < 4; ++j) {
        float* p = &sT[(cw + j) * 68 + ti * 8];
        float4 lo = {a1[0][j], a1[1][j], a1[2][j], a1[3][j]};
        float4 hi = {a1[4][j], a1[5][j], a1[6][j], a1[7][j]};
        *(float4*)p = lo;
        *(float4*)(p + 4) = hi;
    }
    __syncthreads();

    float a2[8][4];
#pragma unroll
    for (int i = 0; i < 8; ++i)
#pragma unroll
        for (int j = 0; j < 4; ++j) a2[i][j] = 0.f;
#pragma unroll 4
    for (int k = 0; k < 64; ++k) {
        const float* ap = &sT[k * 68 + ti * 8];
        float4 alo = *(const float4*)ap;
        float4 ahi = *(const float4*)(ap + 4);
        float4 wv  = *(const float4*)&W2l[k * NH + cw];
        float a8[8] = {alo.x, alo.y, alo.z, alo.w, ahi.x, ahi.y, ahi.z, ahi.w};
        float w4[4] = {wv.x, wv.y, wv.z, wv.w};
#pragma unroll
        for (int i = 0; i < 8; ++i)
#pragma unroll
            for (int j = 0; j < 4; ++j) a2[i][j] += a8[i] * w4[j];
    }

    float s4[4] = {0.f, 0.f, 0.f, 0.f}, q4[4] = {0.f, 0.f, 0.f, 0.f};
    uint2* hBo2 = (uint2*)hBo;
#pragma unroll
    for (int i = 0; i < 8; ++i) {
        int n = base + ti * 8 + i;
        if (n < NND) {
            float o[4];
#pragma unroll
            for (int j = 0; j < 4; ++j) {
                o[j] = fmaxf(a2[i][j], 0.f);
                s4[j] += o[j];
                q4[j] += o[j] * o[j];
            }
            if (outF) *(float4*)&outF[(size_t)n * NH + cw] = *(float4*)&o[0];
            if (hBo) {
                uint2 ov; ov.x = pk(o[0], o[1]); ov.y = pk(o[2], o[3]);
                hBo2[(size_t)n * 16 + wave * 8 + tj] = ov;
            }
        }
    }
#pragma unroll
    for (int m = 1; m < 8; m <<= 1) {
#pragma unroll
        for (int j = 0; j < 4; ++j) {
            s4[j] += __shfl_xor(s4[j], m);
            q4[j] += __shfl_xor(q4[j], m);
        }
    }
    if (ti == 0) {
        int slot = (tile & (NCOPY - 1)) * 128;
#pragma unroll
        for (int j = 0; j < 4; ++j) {
            atomicAdd(&stats[slot + cw + j], s4[j]);
            atomicAdd(&stats[slot + 64 + cw + j], q4[j]);
        }
    }
}

// ---------------- final BN apply, in-place on f32 out; sc/sh derived per block ----------------
__global__ __launch_bounds__(256) void k_bnout(float* __restrict__ h,
                                               const float* __restrict__ stats,
                                               const float* __restrict__ g,
                                               const float* __restrict__ b) {
    __shared__ float sl[128];
    int tid = threadIdx.x;
    if (tid < 64) {
        float sc, sh;
        bn_derive(stats, tid, g, b, sc, sh);
        sl[tid]      = sc;
        sl[64 + tid] = sh;
    }
    __syncthreads();
    int i4 = blockIdx.x * 256 + tid;
    if (i4 < NND * NH / 4) {
        int cg = i4 & 15;
        float4 v   = ((float4*)h)[i4];
        float4 scv = *(float4*)&sl[cg * 4];
        float4 shv = *(float4*)&sl[64 + cg * 4];
        v.x = v.x * scv.x + shv.x;
        v.y = v.y * scv.y + shv.y;
        v.z = v.z * scv.z + shv.z;
        v.w = v.w * scv.w + shv.w;
        ((float4*)h)[i4] = v;
    }
}

extern "C" void kernel_launch(void* const* d_in, const int* in_sizes, int n_in,
                              void* d_out, int out_size, void* d_ws, size_t ws_size,
                              hipStream_t stream) {
    const float* x     = (const float*)d_in[0];
    const int*   ei    = (const int*)d_in[1];
    const float* Wt    = (const float*)d_in[2];
    const float* bt    = (const float*)d_in[3];
    const float* gt    = (const float*)d_in[4];
    const float* bbt   = (const float*)d_in[5];
    const float* W1    = (const float*)d_in[6];
    const float* W2    = (const float*)d_in[7];
    const float* gamma = (const float*)d_in[8];
    const float* beta  = (const float*)d_in[9];
    float* out = (float*)d_out;

    char* ws = (char*)d_ws;
    unsigned* hB    = (unsigned*)(ws + WS_HB);
    unsigned* aggB  = (unsigned*)(ws + WS_AGG);
    float*    stats = (float*)(ws + WS_STATS);   // 4 stage buffers of NCOPY*128
    int*      deg   = (int*)(ws + WS_DEG);
    int*      offs  = (int*)(ws + WS_OFFS);
    int*      cur   = (int*)(ws + WS_CUR);
    int*      parts = (int*)(ws + WS_PARTS);
    int*      esrc  = (int*)(ws + WS_ESRC);

    float* st0 = stats;
    float* st1 = stats + NCOPY * 128;
    float* st2 = stats + 2 * NCOPY * 128;
    float* st3 = stats + 3 * NCOPY * 128;

    const int* srcv = ei;
    const int* dstv = ei + NED;

    // one memset covers all 4 stat buffers + deg (contiguous)
    hipMemsetAsync(stats, 0, 4 * NCOPY * 128 * 4 + NND * 4, stream);

    // fused transform || degree count
    k_dtf<<<NT + PGRID, 256, 0, stream>>>(dstv, deg, x, Wt, bt, hB, st0);
    k_part<<<NSB, SCB, 0, stream>>>(deg, offs, parts);
    k_apply<<<NSB, 256, 0, stream>>>(offs, parts, cur);   // scan2 merged in
    k_fill<<<PGRID, 256, 0, stream>>>(srcv, dstv, cur, esrc);

    const int NB = NND / 4;         // 12500 agg blocks

    // layer 0: BN(st0; g_t) folded into agg
    k_agg<<<NB, 256, 0, stream>>>((const uint4*)hB, (uint4*)aggB, st0, gt, bbt, offs, esrc);
    k_mlp<<<NT, 128, 0, stream>>>((const uint4*)aggB, nullptr, hB, st1, W1, W2);

    // layer 1: BN(st1; gamma[0]) folded into agg
    k_agg<<<NB, 256, 0, stream>>>((const uint4*)hB, (uint4*)aggB, st1, gamma, beta, offs, esrc);
    k_mlp<<<NT, 128, 0, stream>>>((const uint4*)aggB, nullptr, hB, st2, W1 + 4096, W2 + 4096);

    // layer 2: BN(st2; gamma[1]) folded into agg; f32 out for final BN
    k_agg<<<NB, 256, 0, stream>>>((const uint4*)hB, (uint4*)aggB, st2, gamma + 64, beta + 64, offs, esrc);
    k_mlp<<<NT, 128, 0, stream>>>((const uint4*)aggB, out, nullptr, st3, W1 + 8192, W2 + 8192);

    // final BN apply (BN(st3; gamma[2]) derived per block)
    k_bnout<<<(NND * NH / 4 + 255) / 256, 256, 0, stream>>>(out, st3, gamma + 128, beta + 128);
}